// Round 7
// baseline (111.691 us; speedup 1.0000x reference)
//
#include <hip/hip_runtime.h>
#include <hip/hip_bf16.h>
#include <hip/hip_fp16.h>

// CFAR via separable box sums, fp16-interleaved intermediate.
//   hbox    : row prefix (padded LDS) -> horizontal 161/321 window diffs,
//             stored as one __half2 {s161, s321} per pixel (16 MB total)
//   vscan   : in-place per-32-row-segment vertical inclusive scan (fp32
//             accum, half2 storage) + fp32 float2 segment totals
//   segscan : exclusive scan of 32 segment totals per column -> SP (float2)
//   final   : front = P(r+80)-P(r-81), allsum = P(r+160)-P(r-161),
//             P(rho) = hs[rho] + SP[rho>>5] ; out = SCALE*front/(allsum-front)
// BG_AREA = 321^2-161^2 = 77120 ; FRONT_DIV = 161^2*1.8 = 46657.8

#define IMG 4
#define H 1024
#define W 1024
#define NSEG 32
#define SEGR 32
#define PADL 164
#define PADR 164
#define ROWLEN (PADL + W + PADR)   // 1352 floats per padded LDS row

struct h2x4 { __half2 v[4]; };     // 16 B: 4 columns of {s161,s321}
struct f2x4 { float2  v[4]; };     // 32 B: 4 columns of fp32 pairs

// ---------------- Kernel 1: horizontal box sums (both widths) ---------------
// One wave per row. Padded prefix row in LDS (left pad = 0, right pad = row
// total) -> clamp-free phase 2. Phase 2: stride-64 scalar LDS reads (2-way
// aliasing = free), half2-packed scalar coalesced stores (256 B/wave-instr).
__global__ __launch_bounds__(256) void hbox_kernel(const float* __restrict__ x,
                                                   __half2* __restrict__ hs) {
    __shared__ float P[4][ROWLEN];   // 21632 B
    const int wave = threadIdx.x >> 6;
    const int lane = threadIdx.x & 63;
    const int row  = (blockIdx.x << 2) + wave;   // 0..4095 flat over images

    const float4* xr = reinterpret_cast<const float4*>(x + (size_t)row * W);
    float v[16];
    {
        float4 a0 = xr[(lane << 2) + 0];
        float4 a1 = xr[(lane << 2) + 1];
        float4 a2 = xr[(lane << 2) + 2];
        float4 a3 = xr[(lane << 2) + 3];
        v[0]=a0.x; v[1]=a0.y; v[2]=a0.z; v[3]=a0.w;
        v[4]=a1.x; v[5]=a1.y; v[6]=a1.z; v[7]=a1.w;
        v[8]=a2.x; v[9]=a2.y; v[10]=a2.z; v[11]=a2.w;
        v[12]=a3.x; v[13]=a3.y; v[14]=a3.z; v[15]=a3.w;
    }
    float s = 0.f;
#pragma unroll
    for (int j = 0; j < 16; ++j) { s += v[j]; v[j] = s; }
    float t = s;
#pragma unroll
    for (int d = 1; d < 64; d <<= 1) {
        float u = __shfl_up(t, d, 64);
        if (lane >= d) t += u;
    }
    const float off = t - s;           // exclusive prefix of lane totals
#pragma unroll
    for (int j = 0; j < 16; ++j) v[j] += off;
    const float tot = __shfl(t, 63, 64);

    float* rowP = P[wave];
    float4* Pr = reinterpret_cast<float4*>(rowP + PADL);
    Pr[(lane << 2) + 0] = make_float4(v[0], v[1], v[2], v[3]);
    Pr[(lane << 2) + 1] = make_float4(v[4], v[5], v[6], v[7]);
    Pr[(lane << 2) + 2] = make_float4(v[8], v[9], v[10], v[11]);
    Pr[(lane << 2) + 3] = make_float4(v[12], v[13], v[14], v[15]);
    {   // pads: quads 0..40 = 0 (left), quads 297..337 = tot (right)
        float4* Pz = reinterpret_cast<float4*>(rowP);
        if (lane < 41) {
            Pz[lane]       = make_float4(0.f, 0.f, 0.f, 0.f);
            Pz[297 + lane] = make_float4(tot, tot, tot, tot);
        }
    }
    __syncthreads();

    const float* Pw = &P[wave][PADL];
    __half2* oh = hs + (size_t)row * W;
#pragma unroll
    for (int k = 0; k < 16; ++k) {
        const int c = lane + (k << 6);
        const float s1 = Pw[c + 80]  - Pw[c - 81];
        const float s3 = Pw[c + 160] - Pw[c - 161];
        oh[c] = __floats2half2_rn(s1, s3);
    }
}

// ------------- Kernel 2: in-place per-segment column prefix + totals -------
// grid = img(4) x seg(32) x colblk(4) = 512 blocks, 256 threads (1 col each).
__global__ __launch_bounds__(256) void vscan_kernel(__half2* __restrict__ hs,
                                                    float2* __restrict__ Btot) {
    const int bx  = blockIdx.x;
    const int img = bx >> 7;
    const int b7  = bx & 127;
    const int seg = b7 >> 2;
    const int cb  = b7 & 3;
    const int col = (cb << 8) + threadIdx.x;
    const int r0  = seg << 5;

    __half2* p = hs + ((size_t)img << 20) + ((size_t)r0 << 10) + col;
    float a1 = 0.f, a3 = 0.f;
#pragma unroll
    for (int jj = 0; jj < SEGR; jj += 8) {
        __half2 hv[8];
#pragma unroll
        for (int j = 0; j < 8; ++j) hv[j] = p[(size_t)(jj + j) << 10];
#pragma unroll
        for (int j = 0; j < 8; ++j) {
            const float2 f = __half22float2(hv[j]);
            a1 += f.x; a3 += f.y;
            p[(size_t)(jj + j) << 10] = __floats2half2_rn(a1, a3);
        }
    }
    Btot[(((size_t)img * NSEG + seg) << 10) + col] = make_float2(a1, a3);
}

// ------------- Kernel 3: exclusive scan of segment totals per column -------
// 4 imgs x 1024 cols = 4096 threads = 16 blocks x 256.
__global__ __launch_bounds__(256) void segscan_kernel(const float2* __restrict__ Btot,
                                                      float2* __restrict__ SP) {
    const int t   = blockIdx.x * 256 + threadIdx.x;
    const int img = t >> 10;
    const int col = t & 1023;
    const float2* b  = Btot + ((size_t)img * NSEG << 10) + col;
    float2*       sp = SP   + ((size_t)img * NSEG << 10) + col;
    float o1 = 0.f, o3 = 0.f;
#pragma unroll
    for (int sg = 0; sg < NSEG; ++sg) {
        const float2 v = b[(size_t)sg << 10];
        sp[(size_t)sg << 10] = make_float2(o1, o3);
        o1 += v.x; o3 += v.y;
    }
}

// ------------- Kernel 4: final — window diffs of full column prefixes ------
// 512 threads = 2 rows x 256 quad-columns per block; rcp-based division.
__global__ __launch_bounds__(512) void final_kernel(const __half2* __restrict__ hs,
                                                    const float2* __restrict__ SP,
                                                    float* __restrict__ out) {
    const int img = blockIdx.x >> 9;
    const int r   = ((blockIdx.x & 511) << 1) + (threadIdx.x >> 8);
    const int c4  = threadIdx.x & 255;
    const int cb  = c4 << 2;

    const __half2* Hi = hs + ((size_t)img << 20);
    const float2*  Si = SP + ((size_t)img * NSEG << 10);

    const int hi1 = min(r + 80, H - 1),  lo1 = r - 81;
    const int hi3 = min(r + 160, H - 1), lo3 = r - 161;

    float fx[4], ax[4];
    {
        const h2x4 Hh = *reinterpret_cast<const h2x4*>(Hi + ((size_t)hi1 << 10) + cb);
        const f2x4 Sh = *reinterpret_cast<const f2x4*>(Si + (((size_t)hi1 >> 5) << 10) + cb);
#pragma unroll
        for (int i = 0; i < 4; ++i) fx[i] = __half22float2(Hh.v[i]).x + Sh.v[i].x;
    }
    if (lo1 >= 0) {   // block-uniform branch
        const h2x4 Hl = *reinterpret_cast<const h2x4*>(Hi + ((size_t)lo1 << 10) + cb);
        const f2x4 Sl = *reinterpret_cast<const f2x4*>(Si + (((size_t)lo1 >> 5) << 10) + cb);
#pragma unroll
        for (int i = 0; i < 4; ++i) fx[i] -= __half22float2(Hl.v[i]).x + Sl.v[i].x;
    }
    {
        const h2x4 Hh = *reinterpret_cast<const h2x4*>(Hi + ((size_t)hi3 << 10) + cb);
        const f2x4 Sh = *reinterpret_cast<const f2x4*>(Si + (((size_t)hi3 >> 5) << 10) + cb);
#pragma unroll
        for (int i = 0; i < 4; ++i) ax[i] = __half22float2(Hh.v[i]).y + Sh.v[i].y;
    }
    if (lo3 >= 0) {   // block-uniform branch
        const h2x4 Hl = *reinterpret_cast<const h2x4*>(Hi + ((size_t)lo3 << 10) + cb);
        const f2x4 Sl = *reinterpret_cast<const f2x4*>(Si + (((size_t)lo3 >> 5) << 10) + cb);
#pragma unroll
        for (int i = 0; i < 4; ++i) ax[i] -= __half22float2(Hl.v[i]).y + Sl.v[i].y;
    }

    const float SCALE = (float)(77120.0 / 46657.8);   // BG_AREA / FRONT_DIV
    float4 o;
    o.x = SCALE * fx[0] * __builtin_amdgcn_rcpf(ax[0] - fx[0]);
    o.y = SCALE * fx[1] * __builtin_amdgcn_rcpf(ax[1] - fx[1]);
    o.z = SCALE * fx[2] * __builtin_amdgcn_rcpf(ax[2] - fx[2]);
    o.w = SCALE * fx[3] * __builtin_amdgcn_rcpf(ax[3] - fx[3]);
    reinterpret_cast<float4*>(out + ((size_t)img << 20) + ((size_t)r << 10))[c4] = o;
}

extern "C" void kernel_launch(void* const* d_in, const int* in_sizes, int n_in,
                              void* d_out, int out_size, void* d_ws, size_t ws_size,
                              hipStream_t stream) {
    const float* x = (const float*)d_in[0];
    float* outp = (float*)d_out;
    __half2* hs   = (__half2*)d_ws;                              // 16 MB
    float2*  Btot = (float2*)((char*)d_ws + (size_t)IMG * H * W * 4);   // 1 MB
    float2*  SPb  = Btot + (size_t)IMG * NSEG * W;                      // 1 MB

    hbox_kernel<<<dim3((IMG * H) / 4), dim3(256), 0, stream>>>(x, hs);
    vscan_kernel<<<dim3(512), dim3(256), 0, stream>>>(hs, Btot);
    segscan_kernel<<<dim3(16), dim3(256), 0, stream>>>(Btot, SPb);
    final_kernel<<<dim3(IMG * (H / 2)), dim3(512), 0, stream>>>(hs, SPb, outp);
}

// Round 8
// 96.965 us; speedup vs baseline: 1.1519x; 1.1519x over previous
//
#include <hip/hip_runtime.h>
#include <hip/hip_bf16.h>

// CFAR via separable box sums — fused horizontal+vertical-segment scan.
//   hseg    : per-(img, 8-row segment) block: row prefixes (padded LDS) ->
//             horizontal 161/321 window diffs -> 8-row vertical inclusive
//             scan in registers -> scanned g161/g321 + segment totals.
//             Phase-2 uses scalar lane-stride-1 LDS reads (2-way aliasing =
//             free; the b128 variant is 8-way conflicted — measured slower).
//   segscan : exclusive scan of 128 segment totals per column -> SP
//   final   : front = P(r+80)-P(r-81), allsum = P(r+160)-P(r-161),
//             P(rho) = g[rho] + SP[rho>>3] ; out = SCALE*front/(allsum-front)
// BG_AREA = 321^2-161^2 = 77120 ; FRONT_DIV = 161^2*1.8 = 46657.8

#define IMG 4
#define H 1024
#define W 1024
#define SEGR 8
#define NSEG 128                   // H / SEGR
#define PADL 164
#define PADR 164
#define ROWLEN (PADL + W + PADR)   // 1352 floats per padded LDS row

// ---------------- Kernel 1: fused horizontal + 8-row vertical scan ---------
// 512 threads: phase 1 = 8 waves x 1 row each; phase 2 = 512 threads x 2 cols.
__global__ __launch_bounds__(512) void hseg_kernel(const float* __restrict__ x,
                                                   float* __restrict__ g161,
                                                   float* __restrict__ g321,
                                                   float* __restrict__ Btot) {
    __shared__ float P[SEGR][ROWLEN];   // 8*1352*4 = 43264 B
    const int wave = threadIdx.x >> 6;  // 0..7 = local row
    const int lane = threadIdx.x & 63;
    const int img  = blockIdx.x >> 7;
    const int seg  = blockIdx.x & 127;
    const int r0   = seg << 3;

    // ---- phase 1: row prefix into padded LDS ----
    {
        const float4* xr = reinterpret_cast<const float4*>(
            x + (((size_t)img << 10) + r0 + wave) * W);
        float v[16];
        {
            float4 a0 = xr[(lane << 2) + 0];
            float4 a1 = xr[(lane << 2) + 1];
            float4 a2 = xr[(lane << 2) + 2];
            float4 a3 = xr[(lane << 2) + 3];
            v[0]=a0.x; v[1]=a0.y; v[2]=a0.z; v[3]=a0.w;
            v[4]=a1.x; v[5]=a1.y; v[6]=a1.z; v[7]=a1.w;
            v[8]=a2.x; v[9]=a2.y; v[10]=a2.z; v[11]=a2.w;
            v[12]=a3.x; v[13]=a3.y; v[14]=a3.z; v[15]=a3.w;
        }
        float s = 0.f;
#pragma unroll
        for (int j = 0; j < 16; ++j) { s += v[j]; v[j] = s; }
        float t = s;
#pragma unroll
        for (int d = 1; d < 64; d <<= 1) {
            float u = __shfl_up(t, d, 64);
            if (lane >= d) t += u;
        }
        const float off = t - s;         // exclusive prefix of lane totals
#pragma unroll
        for (int j = 0; j < 16; ++j) v[j] += off;
        const float tot = __shfl(t, 63, 64);

        float* rowP = P[wave];
        float4* Pr = reinterpret_cast<float4*>(rowP + PADL);
        Pr[(lane << 2) + 0] = make_float4(v[0], v[1], v[2], v[3]);
        Pr[(lane << 2) + 1] = make_float4(v[4], v[5], v[6], v[7]);
        Pr[(lane << 2) + 2] = make_float4(v[8], v[9], v[10], v[11]);
        Pr[(lane << 2) + 3] = make_float4(v[12], v[13], v[14], v[15]);
        // pads: quads 0..40 = 0 (left), quads 297..337 = tot (right)
        float4* Pz = reinterpret_cast<float4*>(rowP);
        if (lane < 41) {
            Pz[lane]       = make_float4(0.f, 0.f, 0.f, 0.f);
            Pz[297 + lane] = make_float4(tot, tot, tot, tot);
        }
    }
    __syncthreads();

    // ---- phase 2: window diffs + vertical accumulate, 2 cols/thread ----
    const int ca = threadIdx.x;          // col A
    const int cc = threadIdx.x + 512;    // col B
    float s1a = 0.f, s1b = 0.f, s3a = 0.f, s3b = 0.f;
    float* o1 = g161 + ((size_t)img << 20) + ((size_t)r0 << 10);
    float* o3 = g321 + ((size_t)img << 20) + ((size_t)r0 << 10);

#pragma unroll
    for (int j = 0; j < SEGR; ++j) {
        const float* Pw = &P[j][PADL];
        s1a += Pw[ca + 80]  - Pw[ca - 81];
        s3a += Pw[ca + 160] - Pw[ca - 161];
        s1b += Pw[cc + 80]  - Pw[cc - 81];
        s3b += Pw[cc + 160] - Pw[cc - 161];
        o1[(j << 10) + ca] = s1a;
        o1[(j << 10) + cc] = s1b;
        o3[(j << 10) + ca] = s3a;
        o3[(j << 10) + cc] = s3b;
    }
    // segment totals, layout [buf][img][seg][W]
    float* b1 = Btot + (((size_t)img * NSEG) + seg) * W;
    float* b3 = Btot + (((size_t)(IMG + img) * NSEG) + seg) * W;
    b1[ca] = s1a; b1[cc] = s1b;
    b3[ca] = s3a; b3[cc] = s3b;
}

// ------------- Kernel 2: exclusive scan of segment totals per column -------
// 2 bufs x 4 imgs x 1024 cols = 8192 threads = 32 blocks x 256.
__global__ __launch_bounds__(256) void segscan_kernel(const float* __restrict__ Btot,
                                                      float* __restrict__ SP) {
    const int t = blockIdx.x * 256 + threadIdx.x;     // (buf*4+img)*1024 + col
    const size_t base = (size_t)(t >> 10) * NSEG * W + (t & 1023);
    const float* b = Btot + base;
    float* sp = SP + base;
    float off = 0.f;
#pragma unroll 8
    for (int sg = 0; sg < NSEG; ++sg) {
        const float v = b[(size_t)sg << 10];
        sp[(size_t)sg << 10] = off;
        off += v;
    }
}

// ------------- Kernel 3: final — window diffs of full column prefixes ------
// 512 threads = 2 rows x 256 quad-columns per block; rcp-based division.
__global__ __launch_bounds__(512) void final_kernel(const float* __restrict__ g161,
                                                    const float* __restrict__ g321,
                                                    const float* __restrict__ SP,
                                                    float* __restrict__ out) {
    const int img = blockIdx.x >> 9;
    const int r   = ((blockIdx.x & 511) << 1) + (threadIdx.x >> 8);
    const int c4  = threadIdx.x & 255;

    const float4* P1 = reinterpret_cast<const float4*>(g161 + ((size_t)img << 20));
    const float4* P3 = reinterpret_cast<const float4*>(g321 + ((size_t)img << 20));
    // SP float4 layout: [buf][img][NSEG][256] ; NSEG*256 = 1<<15 per (buf,img)
    const float4* SP1 = reinterpret_cast<const float4*>(SP) + ((size_t)img << 15);
    const float4* SP3 = reinterpret_cast<const float4*>(SP) + ((size_t)(IMG + img) << 15);

    const int hi1 = min(r + 80, H - 1),  lo1 = r - 81;
    const int hi3 = min(r + 160, H - 1), lo3 = r - 161;

    float4 f  = P1[((size_t)hi1 << 8) + c4];
    float4 fs = SP1[(((size_t)hi1 >> 3) << 8) + c4];
    float fx = f.x + fs.x, fy = f.y + fs.y, fz = f.z + fs.z, fw = f.w + fs.w;
    if (lo1 >= 0) {   // block-uniform branch
        float4 g  = P1[((size_t)lo1 << 8) + c4];
        float4 gs = SP1[(((size_t)lo1 >> 3) << 8) + c4];
        fx -= g.x + gs.x; fy -= g.y + gs.y; fz -= g.z + gs.z; fw -= g.w + gs.w;
    }
    float4 a  = P3[((size_t)hi3 << 8) + c4];
    float4 as = SP3[(((size_t)hi3 >> 3) << 8) + c4];
    float ax = a.x + as.x, ay = a.y + as.y, az = a.z + as.z, aw = a.w + as.w;
    if (lo3 >= 0) {   // block-uniform branch
        float4 g  = P3[((size_t)lo3 << 8) + c4];
        float4 gs = SP3[(((size_t)lo3 >> 3) << 8) + c4];
        ax -= g.x + gs.x; ay -= g.y + gs.y; az -= g.z + gs.z; aw -= g.w + gs.w;
    }

    const float SCALE = (float)(77120.0 / 46657.8);   // BG_AREA / FRONT_DIV
    float4 o;
    o.x = SCALE * fx * __builtin_amdgcn_rcpf(ax - fx);
    o.y = SCALE * fy * __builtin_amdgcn_rcpf(ay - fy);
    o.z = SCALE * fz * __builtin_amdgcn_rcpf(az - fz);
    o.w = SCALE * fw * __builtin_amdgcn_rcpf(aw - fw);
    reinterpret_cast<float4*>(out + ((size_t)img << 20) + ((size_t)r << 10))[c4] = o;
}

extern "C" void kernel_launch(void* const* d_in, const int* in_sizes, int n_in,
                              void* d_out, int out_size, void* d_ws, size_t ws_size,
                              hipStream_t stream) {
    const float* x = (const float*)d_in[0];
    float* outp = (float*)d_out;
    float* g161 = (float*)d_ws;                               // 16 MB
    float* g321 = g161 + (size_t)IMG * H * W;                 // 16 MB
    float* Btot = g321 + (size_t)IMG * H * W;                 // 2*4*128*1024*4 = 4 MB
    float* SPb  = Btot + (size_t)2 * IMG * NSEG * W;          // 4 MB

    hseg_kernel<<<dim3(IMG * NSEG), dim3(512), 0, stream>>>(x, g161, g321, Btot);
    segscan_kernel<<<dim3(32), dim3(256), 0, stream>>>(Btot, SPb);
    final_kernel<<<dim3(IMG * (H / 2)), dim3(512), 0, stream>>>(g161, g321, SPb, outp);
}

// Round 9
// 95.112 us; speedup vs baseline: 1.1743x; 1.0195x over previous
//
#include <hip/hip_runtime.h>
#include <hip/hip_bf16.h>

// CFAR via separable box sums (R6 structure; vscan vectorized, segscan
// parallelized by wave shuffle-scan).
//   hbox    : row prefix (padded LDS) -> horizontal 161/321 window diffs
//   vscan   : in-place per-32-row-segment vertical inclusive scan (float4
//             per thread) + seg totals
//   segscan : exclusive scan of 32 segment totals per column — one wave per
//             2 columns, shuffle-scan over lanes
//   final   : front = P(r+80)-P(r-81), allsum = P(r+160)-P(r-161),
//             P(rho) = g[rho] + SP[rho>>5] ; out = SCALE*front/(allsum-front)
// BG_AREA = 321^2-161^2 = 77120 ; FRONT_DIV = 161^2*1.8 = 46657.8

#define IMG 4
#define H 1024
#define W 1024
#define NSEG 32
#define SEGR 32
#define PADL 164
#define PADR 164
#define ROWLEN (PADL + W + PADR)   // 1352 floats per padded LDS row

// ---------------- Kernel 1: horizontal box sums (both widths) ---------------
// One wave per row. Padded prefix row in LDS (left pad = 0, right pad = row
// total) -> clamp-free phase 2. Phase 2: stride-64 scalar LDS reads (2-way
// aliasing = free), scalar coalesced global stores. [R6-proven]
__global__ __launch_bounds__(256) void hbox_kernel(const float* __restrict__ x,
                                                   float* __restrict__ h161,
                                                   float* __restrict__ h321) {
    __shared__ float P[4][ROWLEN];   // 21632 B
    const int wave = threadIdx.x >> 6;
    const int lane = threadIdx.x & 63;
    const int row  = (blockIdx.x << 2) + wave;   // 0..4095 flat over images

    const float4* xr = reinterpret_cast<const float4*>(x + (size_t)row * W);
    float v[16];
    {
        float4 a0 = xr[(lane << 2) + 0];
        float4 a1 = xr[(lane << 2) + 1];
        float4 a2 = xr[(lane << 2) + 2];
        float4 a3 = xr[(lane << 2) + 3];
        v[0]=a0.x; v[1]=a0.y; v[2]=a0.z; v[3]=a0.w;
        v[4]=a1.x; v[5]=a1.y; v[6]=a1.z; v[7]=a1.w;
        v[8]=a2.x; v[9]=a2.y; v[10]=a2.z; v[11]=a2.w;
        v[12]=a3.x; v[13]=a3.y; v[14]=a3.z; v[15]=a3.w;
    }
    float s = 0.f;
#pragma unroll
    for (int j = 0; j < 16; ++j) { s += v[j]; v[j] = s; }
    float t = s;
#pragma unroll
    for (int d = 1; d < 64; d <<= 1) {
        float u = __shfl_up(t, d, 64);
        if (lane >= d) t += u;
    }
    const float off = t - s;           // exclusive prefix of lane totals
#pragma unroll
    for (int j = 0; j < 16; ++j) v[j] += off;
    const float tot = __shfl(t, 63, 64);

    float* rowP = P[wave];
    float4* Pr = reinterpret_cast<float4*>(rowP + PADL);
    Pr[(lane << 2) + 0] = make_float4(v[0], v[1], v[2], v[3]);
    Pr[(lane << 2) + 1] = make_float4(v[4], v[5], v[6], v[7]);
    Pr[(lane << 2) + 2] = make_float4(v[8], v[9], v[10], v[11]);
    Pr[(lane << 2) + 3] = make_float4(v[12], v[13], v[14], v[15]);
    {   // pads: quads 0..40 = 0 (left), quads 297..337 = tot (right)
        float4* Pz = reinterpret_cast<float4*>(rowP);
        if (lane < 41) {
            Pz[lane]       = make_float4(0.f, 0.f, 0.f, 0.f);
            Pz[297 + lane] = make_float4(tot, tot, tot, tot);
        }
    }
    __syncthreads();

    const float* Pw = &P[wave][PADL];
    float* o161 = h161 + (size_t)row * W;
    float* o321 = h321 + (size_t)row * W;
#pragma unroll
    for (int k = 0; k < 16; ++k) {
        const int c = lane + (k << 6);
        const float s1 = Pw[c + 80]  - Pw[c - 81];
        const float s3 = Pw[c + 160] - Pw[c - 161];
        o161[c] = s1;
        o321[c] = s3;
    }
}

// ------------- Kernel 2: in-place per-segment column prefix + totals -------
// float4 per thread: block = (img, seg), 256 threads = 256 quad-columns.
// grid.x = 4*32 = 128, grid.y = buffer (0:h161, 1:h321).
__global__ __launch_bounds__(256) void vscan_kernel(float* __restrict__ h161,
                                                    float* __restrict__ h321,
                                                    float* __restrict__ Btot) {
    const int img = blockIdx.x >> 5;
    const int seg = blockIdx.x & 31;
    const int q   = threadIdx.x;          // quad column 0..255
    const int r0  = seg << 5;

    float* buf = blockIdx.y ? h321 : h161;
    float4* p = reinterpret_cast<float4*>(buf + ((size_t)img << 20) + ((size_t)r0 << 10)) + q;

    float ax = 0.f, ay = 0.f, az = 0.f, aw = 0.f;
#pragma unroll
    for (int jj = 0; jj < SEGR; jj += 8) {
        float4 a[8];
#pragma unroll
        for (int j = 0; j < 8; ++j) a[j] = p[(size_t)(jj + j) << 8];
#pragma unroll
        for (int j = 0; j < 8; ++j) {
            ax += a[j].x; ay += a[j].y; az += a[j].z; aw += a[j].w;
            a[j] = make_float4(ax, ay, az, aw);
        }
#pragma unroll
        for (int j = 0; j < 8; ++j) p[(size_t)(jj + j) << 8] = a[j];
    }
    // totals, layout float [buf][img][seg][W]
    float4* bt = reinterpret_cast<float4*>(
        Btot + ((((size_t)blockIdx.y << 2) + img) << 15) + ((size_t)seg << 10));
    bt[q] = make_float4(ax, ay, az, aw);
}

// ------------- Kernel 3: exclusive scan of segment totals per column -------
// One wave per 2 columns: lanes 0..31 = col A's 32 segs, 32..63 = col B's.
// Gather load -> 5-step shuffle scan (guarded at 32-lane boundary) -> store.
// 4096 waves = 1024 blocks x 256.
__global__ __launch_bounds__(256) void segscan_kernel(const float* __restrict__ Btot,
                                                      float* __restrict__ SP) {
    const int wid    = (blockIdx.x << 2) + (threadIdx.x >> 6);  // 0..4095
    const int lane   = threadIdx.x & 63;
    const int bufimg = wid >> 9;                                // 0..7
    const int pairk  = wid & 511;                               // 0..511
    const int col    = (pairk << 1) + (lane >> 5);
    const int segl   = lane & 31;

    const size_t idx = ((size_t)bufimg << 15) + ((size_t)segl << 10) + col;
    const float v = Btot[idx];
    float t = v;
#pragma unroll
    for (int d = 1; d < 32; d <<= 1) {
        const float u = __shfl_up(t, d, 64);
        if ((lane & 31) >= d) t += u;
    }
    SP[idx] = t - v;   // exclusive prefix
}

// ------------- Kernel 4: final — window diffs of full column prefixes ------
// 512 threads = 2 rows x 256 quad-columns per block; rcp-based division.
__global__ __launch_bounds__(512) void final_kernel(const float* __restrict__ g161,
                                                    const float* __restrict__ g321,
                                                    const float* __restrict__ SP,
                                                    float* __restrict__ out) {
    const int img = blockIdx.x >> 9;
    const int r   = ((blockIdx.x & 511) << 1) + (threadIdx.x >> 8);
    const int c4  = threadIdx.x & 255;

    const float4* P1 = reinterpret_cast<const float4*>(g161 + ((size_t)img << 20));
    const float4* P3 = reinterpret_cast<const float4*>(g321 + ((size_t)img << 20));
    // SP float4 layout: [buf][img][NSEG][256] ; NSEG*256 = 1<<13 per (buf,img)
    const float4* SP1 = reinterpret_cast<const float4*>(SP) + ((size_t)img << 13);
    const float4* SP3 = reinterpret_cast<const float4*>(SP) + ((size_t)(IMG + img) << 13);

    const int hi1 = min(r + 80, H - 1),  lo1 = r - 81;
    const int hi3 = min(r + 160, H - 1), lo3 = r - 161;

    float4 f  = P1[((size_t)hi1 << 8) + c4];
    float4 fs = SP1[(((size_t)hi1 >> 5) << 8) + c4];
    float fx = f.x + fs.x, fy = f.y + fs.y, fz = f.z + fs.z, fw = f.w + fs.w;
    if (lo1 >= 0) {
        float4 g  = P1[((size_t)lo1 << 8) + c4];
        float4 gs = SP1[(((size_t)lo1 >> 5) << 8) + c4];
        fx -= g.x + gs.x; fy -= g.y + gs.y; fz -= g.z + gs.z; fw -= g.w + gs.w;
    }
    float4 a  = P3[((size_t)hi3 << 8) + c4];
    float4 as = SP3[(((size_t)hi3 >> 5) << 8) + c4];
    float ax = a.x + as.x, ay = a.y + as.y, az = a.z + as.z, aw = a.w + as.w;
    if (lo3 >= 0) {
        float4 g  = P3[((size_t)lo3 << 8) + c4];
        float4 gs = SP3[(((size_t)lo3 >> 5) << 8) + c4];
        ax -= g.x + gs.x; ay -= g.y + gs.y; az -= g.z + gs.z; aw -= g.w + gs.w;
    }

    const float SCALE = (float)(77120.0 / 46657.8);   // BG_AREA / FRONT_DIV
    float4 o;
    o.x = SCALE * fx * __builtin_amdgcn_rcpf(ax - fx);
    o.y = SCALE * fy * __builtin_amdgcn_rcpf(ay - fy);
    o.z = SCALE * fz * __builtin_amdgcn_rcpf(az - fz);
    o.w = SCALE * fw * __builtin_amdgcn_rcpf(aw - fw);
    reinterpret_cast<float4*>(out + ((size_t)img << 20) + ((size_t)r << 10))[c4] = o;
}

extern "C" void kernel_launch(void* const* d_in, const int* in_sizes, int n_in,
                              void* d_out, int out_size, void* d_ws, size_t ws_size,
                              hipStream_t stream) {
    const float* x = (const float*)d_in[0];
    float* outp = (float*)d_out;
    float* h161 = (float*)d_ws;                          // 16 MB
    float* h321 = h161 + (size_t)IMG * H * W;            // 16 MB
    float* Btot = h321 + (size_t)IMG * H * W;            // 1 MB (2*4*32*1024 fp32)
    float* SPb  = Btot + (size_t)2 * IMG * NSEG * W;     // 1 MB

    hbox_kernel<<<dim3((IMG * H) / 4), dim3(256), 0, stream>>>(x, h161, h321);
    vscan_kernel<<<dim3(128, 2), dim3(256), 0, stream>>>(h161, h321, Btot);
    segscan_kernel<<<dim3(1024), dim3(256), 0, stream>>>(Btot, SPb);
    final_kernel<<<dim3(IMG * (H / 2)), dim3(512), 0, stream>>>(h161, h321, SPb, outp);
}